// Round 10
// baseline (269.554 us; speedup 1.0000x reference)
//
#include <hip/hip_runtime.h>
#include <stdint.h>

typedef short short8 __attribute__((ext_vector_type(8)));
typedef float floatx16 __attribute__((ext_vector_type(16)));
typedef unsigned int uint32;

#define NPTS (4 * 65536)
#define RGB_OFF (NPTS * 3)

// ---------- helpers ----------
__device__ __forceinline__ uint16_t bf_rne(float f) {
  uint32 u = __float_as_uint(f);
  u += 0x7FFFu + ((u >> 16) & 1u);
  return (uint16_t)(u >> 16);
}
// pack two f32 -> two bf16 (round-half-up) via v_perm_b32
__device__ __forceinline__ uint32 pack2(float a, float b) {
  return __builtin_amdgcn_perm(__float_as_uint(b) + 0x8000u,
                               __float_as_uint(a) + 0x8000u, 0x07060302u);
}
__device__ __forceinline__ float bf_lo(uint32 u) { return __uint_as_float(u << 16); }
__device__ __forceinline__ float bf_hi(uint32 u) { return __uint_as_float(u & 0xFFFF0000u); }
// exchange: a's upper 32 lanes <-> b's lower 32 lanes
__device__ __forceinline__ void swap32(uint32& a, uint32& b) {
  asm("v_permlane32_swap_b32 %0, %1" : "+v"(a), "+v"(b));
}
__device__ __forceinline__ void gacc(const uint16_t* p, float w, float* acc) {
  uint4 q = *(const uint4*)p;
  acc[0] += w * bf_lo(q.x);
  acc[1] += w * bf_hi(q.x);
  acc[2] += w * bf_lo(q.y);
  acc[3] += w * bf_hi(q.y);
  acc[4] += w * bf_lo(q.z);
  acc[5] += w * bf_hi(q.z);
  acc[6] += w * bf_lo(q.w);
  acc[7] += w * bf_hi(q.w);
}

// ---------- kernel 1: triplane (12,32,256,256) f32 -> (12,256,256,32) bf16 ----------
// Streaming, LDS-free: thread = output pixel, 32 coalesced channel reads,
// one contiguous 64B store.
__global__ __launch_bounds__(256) void k_tr(const float* __restrict__ tri,
                                            uint16_t* __restrict__ out) {
  const size_t P = (size_t)blockIdx.x * 256 + threadIdx.x;  // pixel 0..786431
  const int n = (int)(P >> 16);
  const int rem = (int)(P & 65535);
  const float* src = tri + ((size_t)n << 21) + rem;
  uint32 q[16];
#pragma unroll
  for (int c = 0; c < 16; ++c) {
    float a = src[(size_t)(2 * c) << 16];
    float b = src[(size_t)(2 * c + 1) << 16];
    q[c] = pack2(a, b);
  }
  uint4* dst = (uint4*)(out + P * 32);
  dst[0] = make_uint4(q[0], q[1], q[2], q[3]);
  dst[1] = make_uint4(q[4], q[5], q[6], q[7]);
  dst[2] = make_uint4(q[8], q[9], q[10], q[11]);
  dst[3] = make_uint4(q[12], q[13], q[14], q[15]);
}

// ---------- kernel 2: pack weights into MFMA A-frag layout + biases into C-layout ----------
// frag bases per layer: {0,20,52,84,104,136,168}, Ks={5,8,8,5,8,8,8}, 176 frags.
// frag(lay,mt,k): lane L holds W[mt*32+(L&31)][k*16+(L>>5)*8 + j], j=0..7 -> 16B
// packed-h column order: [feats 0..31 | freq 32..67 | pad 68..79].
__global__ __launch_bounds__(256) void k_pack(
    const float* __restrict__ w_in, const float* __restrict__ w_skip,
    const float* __restrict__ w_before, const float* __restrict__ w_after,
    const float* __restrict__ w_out, const float* __restrict__ b_in,
    const float* __restrict__ b_skip, const float* __restrict__ b_before,
    const float* __restrict__ b_after, const float* __restrict__ b_out,
    uint16_t* __restrict__ wpack, float* __restrict__ bpack) {
  const int blk = blockIdx.x;
  if (blk >= 44) {  // bias pack: bpack[l*128 + mt*32 + half*16 + reg]
    for (int t = threadIdx.x; t < 800; t += 256) {
      int l, idx;
      if (t < 768) { l = t >> 7; idx = t & 127; }
      else { l = 6; idx = t - 768; }
      int mt = idx >> 5, rem = idx & 31;
      int half = rem >> 4, r = rem & 15;
      int f = mt * 32 + (r & 3) + 8 * (r >> 2) + 4 * half;
      float v;
      switch (l) {
        case 0: v = b_in[f]; break;
        case 1: v = b_before[f]; break;
        case 2: v = b_before[128 + f]; break;
        case 3: v = b_skip[f]; break;
        case 4: v = b_after[f]; break;
        case 5: v = b_after[128 + f]; break;
        default: v = (f < 4) ? b_out[f] : 0.0f; break;
      }
      bpack[l * 128 + idx] = v;
    }
    return;
  }
  const int w = blk * 4 + (threadIdx.x >> 6);  // 0..175
  const int L = threadIdx.x & 63;
  int lay, mt, k;
  if (w < 20)      { lay = 0; mt = w / 5;        k = w - mt * 5; }
  else if (w < 52) { int u = w - 20;  lay = 1; mt = u >> 3; k = u & 7; }
  else if (w < 84) { int u = w - 52;  lay = 2; mt = u >> 3; k = u & 7; }
  else if (w < 104){ int u = w - 84;  lay = 3; mt = u / 5;  k = u - mt * 5; }
  else if (w < 136){ int u = w - 104; lay = 4; mt = u >> 3; k = u & 7; }
  else if (w < 168){ int u = w - 136; lay = 5; mt = u >> 3; k = u & 7; }
  else             { lay = 6; mt = 0; k = w - 168; }
  const float* W;
  int insk = 0;
  switch (lay) {
    case 0: W = w_in; insk = 1; break;
    case 1: W = w_before; break;
    case 2: W = w_before + 16384; break;
    case 3: W = w_skip; insk = 1; break;
    case 4: W = w_after; break;
    case 5: W = w_after + 16384; break;
    default: W = w_out; break;
  }
  const int frow = mt * 32 + (L & 31);
  const int kbase = k * 16 + (L >> 5) * 8;
  uint16_t h[8];
#pragma unroll
  for (int j = 0; j < 8; ++j) {
    int kl = kbase + j;
    float v;
    if (insk) {
      int col = (kl < 32) ? (36 + kl) : ((kl < 68) ? (kl - 32) : -1);
      v = (col < 0) ? 0.0f : W[frow * 68 + col];
    } else if (lay == 6) {
      v = (frow < 4) ? W[frow * 128 + kl] : 0.0f;
    } else {
      v = W[frow * 128 + kl];
    }
    h[j] = bf_rne(v);
  }
  uint4 q;
  q.x = (uint32)h[0] | ((uint32)h[1] << 16);
  q.y = (uint32)h[2] | ((uint32)h[3] << 16);
  q.z = (uint32)h[4] | ((uint32)h[5] << 16);
  q.w = (uint32)h[6] | ((uint32)h[7] << 16);
  *(uint4*)(wpack + (size_t)w * 512 + L * 8) = q;
}

// ---------- weight staging: global -> LDS, cooperative over 256 threads ----------
// NFRAG KB copied; chunk counts are multiples of 256 for all layers (no bounds).
template <int NFRAG>
__device__ __forceinline__ void stage(const uint16_t* __restrict__ wp_base,
                                      uint16_t* __restrict__ wbuf, int t) {
#pragma unroll
  for (int i = 0; i < NFRAG * 64 / 256; ++i) {
    const int g = t + i * 256;  // 16B chunk index
    uint4 v = *(const uint4*)(wp_base + g * 8);
    *(uint4*)(wbuf + g * 8) = v;
  }
}

// ---------- register-resident MLP machinery (weights from LDS) ----------
template <int LAY, int Ks>
__device__ __forceinline__ void mfma_block(floatx16* a, const short8* bin,
                                           const uint16_t* __restrict__ wbuf,
                                           const float* __restrict__ bpack, int L,
                                           int kh) {
#pragma unroll
  for (int mt = 0; mt < 4; ++mt) {
    const float4* bp = (const float4*)(bpack + LAY * 128 + mt * 32 + kh * 16);
#pragma unroll
    for (int g = 0; g < 4; ++g) {
      float4 v = bp[g];
      a[mt][4 * g + 0] = v.x; a[mt][4 * g + 1] = v.y;
      a[mt][4 * g + 2] = v.z; a[mt][4 * g + 3] = v.w;
    }
  }
  const uint16_t* wp = wbuf + L * 8;
#pragma unroll
  for (int k = 0; k < Ks; ++k) {
    short8 w0 = *(const short8*)(wp + (size_t)(0 * Ks + k) * 512);
    short8 w1 = *(const short8*)(wp + (size_t)(1 * Ks + k) * 512);
    short8 w2 = *(const short8*)(wp + (size_t)(2 * Ks + k) * 512);
    short8 w3 = *(const short8*)(wp + (size_t)(3 * Ks + k) * 512);
    a[0] = __builtin_amdgcn_mfma_f32_32x32x16_bf16(w0, bin[k], a[0], 0, 0, 0);
    a[1] = __builtin_amdgcn_mfma_f32_32x32x16_bf16(w1, bin[k], a[1], 0, 0, 0);
    a[2] = __builtin_amdgcn_mfma_f32_32x32x16_bf16(w2, bin[k], a[2], 0, 0, 0);
    a[3] = __builtin_amdgcn_mfma_f32_32x32x16_bf16(w3, bin[k], a[3], 0, 0, 0);
  }
}

template <int LAY, int Ks>
__device__ __forceinline__ void layer_dense(const short8* bin, short8* bout,
                                            const uint16_t* __restrict__ wbuf,
                                            const float* __restrict__ bpack, int L,
                                            int kh) {
  floatx16 a[4];
  mfma_block<LAY, Ks>(a, bin, wbuf, bpack, L, kh);
#pragma unroll
  for (int f = 0; f < 8; ++f) {
    const int mt = f >> 1, s = f & 1;
    uint32 q0a = pack2(fmaxf(a[mt][8 * s + 0], 0.f), fmaxf(a[mt][8 * s + 1], 0.f));
    uint32 q0b = pack2(fmaxf(a[mt][8 * s + 2], 0.f), fmaxf(a[mt][8 * s + 3], 0.f));
    uint32 q1a = pack2(fmaxf(a[mt][8 * s + 4], 0.f), fmaxf(a[mt][8 * s + 5], 0.f));
    uint32 q1b = pack2(fmaxf(a[mt][8 * s + 6], 0.f), fmaxf(a[mt][8 * s + 7], 0.f));
    swap32(q0a, q1a);
    swap32(q0b, q1b);
    bout[f] = __builtin_bit_cast(short8, make_uint4(q0a, q0b, q1a, q1b));
  }
}

template <int LAY, int Ks>
__device__ __forceinline__ void layer_skip(const short8* hin, short8* bio,
                                           const uint16_t* __restrict__ wbuf,
                                           const float* __restrict__ bpack, int L,
                                           int kh) {
  floatx16 a[4];
  mfma_block<LAY, Ks>(a, hin, wbuf, bpack, L, kh);
#pragma unroll
  for (int f = 0; f < 8; ++f) {
    const int mt = f >> 1, s = f & 1;
    uint4 old = __builtin_bit_cast(uint4, bio[f]);
    uint32 uA = old.x, uB = old.y, uC = old.z, uD = old.w;
    swap32(uA, uC);  // involution: back to C-layout packed x2
    swap32(uB, uD);
    float r0 = fmaxf(a[mt][8 * s + 0], 0.f) + bf_lo(uA);
    float r1 = fmaxf(a[mt][8 * s + 1], 0.f) + bf_hi(uA);
    float r2 = fmaxf(a[mt][8 * s + 2], 0.f) + bf_lo(uB);
    float r3 = fmaxf(a[mt][8 * s + 3], 0.f) + bf_hi(uB);
    float r4 = fmaxf(a[mt][8 * s + 4], 0.f) + bf_lo(uC);
    float r5 = fmaxf(a[mt][8 * s + 5], 0.f) + bf_hi(uC);
    float r6 = fmaxf(a[mt][8 * s + 6], 0.f) + bf_lo(uD);
    float r7 = fmaxf(a[mt][8 * s + 7], 0.f) + bf_hi(uD);
    uint32 q0a = pack2(r0, r1), q0b = pack2(r2, r3);
    uint32 q1a = pack2(r4, r5), q1b = pack2(r6, r7);
    swap32(q0a, q1a);
    swap32(q0b, q1b);
    bio[f] = __builtin_bit_cast(short8, make_uint4(q0a, q0b, q1a, q1b));
  }
}

// ---------- kernel 3: fused gather + encode + MLP ----------
// Wave owns 32 points; activations register-resident; weights staged layer-by-layer
// into a single 32KB LDS buffer shared by the block's 4 waves.
__global__ __launch_bounds__(256, 3) void k_main(
    const uint16_t* __restrict__ trit, const float* __restrict__ trif,
    const float* __restrict__ coords, const uint16_t* __restrict__ wpack,
    const float* __restrict__ bpack, float* __restrict__ dout, int fast) {
  __shared__ __align__(16) uint16_t wbuf[16384];  // 32KB: one layer's frags
  const int t = threadIdx.x;
  const int L = t & 63;
  const int kh = L >> 5;
  const int p = (t >> 6) * 32 + (L & 31);
  const int pg = blockIdx.x * 128 + p;

  // stage layer-0 weights early; copy overlaps the gather loads below
  stage<20>(wpack, wbuf, t);

  // ---- phase 1: gather + freq encode, directly into B-frag registers ----
  float cx = coords[pg * 3 + 0], cy = coords[pg * 3 + 1], cz = coords[pg * 3 + 2];
  float f1x = cx + 1.0f, f1y = cy + 1.0f, f1z = cz + 1.0f;
  float nx = f1x * 0.5f, ny = f1y * 0.5f, nz = f1z * 0.5f;
  float sx = f1x - 1.0f, sy = f1y - 1.0f, sz = f1z - 1.0f;
  bool sel = (nx > 0.f) & (nx < 1.f) & (ny > 0.f) & (ny < 1.f) & (nz > 0.f) & (nz < 1.f);
  const int b = pg >> 16;
  float acc[16];
#pragma unroll
  for (int j = 0; j < 16; ++j) acc[j] = 0.f;
#pragma unroll
  for (int pl = 0; pl < 3; ++pl) {
    float gx = (pl == 2) ? sy : sx;
    float gy = (pl == 0) ? sy : sz;
    float ix = ((gx + 1.0f) * 0.5f) * 255.0f;
    float iy = ((gy + 1.0f) * 0.5f) * 255.0f;
    float x0f = floorf(ix), y0f = floorf(iy);
    float wx = ix - x0f, wy = iy - y0f;
    float vx0 = (x0f >= 0.0f && x0f < 256.0f) ? 1.f : 0.f;
    float vx1 = (x0f >= -1.0f && x0f < 255.0f) ? 1.f : 0.f;
    float vy0 = (y0f >= 0.0f && y0f < 256.0f) ? 1.f : 0.f;
    float vy1 = (y0f >= -1.0f && y0f < 255.0f) ? 1.f : 0.f;
    int x0 = min(max((int)x0f, 0), 255), x1 = min(max((int)x0f + 1, 0), 255);
    int y0 = min(max((int)y0f, 0), 255), y1 = min(max((int)y0f + 1, 0), 255);
    float w00 = (1.f - wx) * (1.f - wy) * vx0 * vy0;
    float w10 = wx * (1.f - wy) * vx1 * vy0;
    float w01 = (1.f - wx) * wy * vx0 * vy1;
    float w11 = wx * wy * vx1 * vy1;
    const int n = 3 * b + pl;
    if (fast) {
      // lane's channel chunks: [kh*8, kh*8+8) and [16+kh*8, ...)
      const uint16_t* cb = trit + ((size_t)n << 21) + kh * 8;
      size_t o00 = (size_t)(y0 * 256 + x0) << 5, o10 = (size_t)(y0 * 256 + x1) << 5;
      size_t o01 = (size_t)(y1 * 256 + x0) << 5, o11 = (size_t)(y1 * 256 + x1) << 5;
      gacc(cb + o00, w00, acc); gacc(cb + 16 + o00, w00, acc + 8);
      gacc(cb + o10, w10, acc); gacc(cb + 16 + o10, w10, acc + 8);
      gacc(cb + o01, w01, acc); gacc(cb + 16 + o01, w01, acc + 8);
      gacc(cb + o11, w11, acc); gacc(cb + 16 + o11, w11, acc + 8);
    } else {
      const float* basef = trif + (((size_t)n * 32) << 16);
#pragma unroll
      for (int j = 0; j < 8; ++j) {
        const float* c0p = basef + (((size_t)(kh * 8 + j)) << 16);
        const float* c1p = basef + (((size_t)(16 + kh * 8 + j)) << 16);
        acc[j] += w00 * c0p[y0 * 256 + x0] + w10 * c0p[y0 * 256 + x1] +
                  w01 * c0p[y1 * 256 + x0] + w11 * c0p[y1 * 256 + x1];
        acc[8 + j] += w00 * c1p[y0 * 256 + x0] + w10 * c1p[y0 * 256 + x1] +
                      w01 * c1p[y1 * 256 + x0] + w11 * c1p[y1 * 256 + x1];
      }
    }
  }
  short8 hf[5];
  hf[0] = __builtin_bit_cast(
      short8, make_uint4(pack2(acc[0], acc[1]), pack2(acc[2], acc[3]),
                         pack2(acc[4], acc[5]), pack2(acc[6], acc[7])));
  hf[1] = __builtin_bit_cast(
      short8, make_uint4(pack2(acc[8], acc[9]), pack2(acc[10], acc[11]),
                         pack2(acc[12], acc[13]), pack2(acc[14], acc[15])));
  {
    // freq cols 32+e, e = d*12 + (sin: k | cos: 6+k)
    float sv[3][6], cv[3][6];
#pragma unroll
    for (int d = 0; d < 3; ++d) {
      float nd = (d == 0) ? nx : (d == 1) ? ny : nz;
#pragma unroll
      for (int k = 0; k < 6; ++k) {
        float rev = nd * (0.5f * (float)(1 << k));
        float r = rev - rintf(rev);
        sv[d][k] = __builtin_amdgcn_sinf(r);
        cv[d][k] = __builtin_amdgcn_cosf(r);
      }
    }
    if (kh == 0) {
      hf[2] = __builtin_bit_cast(  // e 0..7: d0 s0-5, d0 c0-1
          short8, make_uint4(pack2(sv[0][0], sv[0][1]), pack2(sv[0][2], sv[0][3]),
                             pack2(sv[0][4], sv[0][5]), pack2(cv[0][0], cv[0][1])));
      hf[3] = __builtin_bit_cast(  // e 16..23: d1 s4-5, d1 c0-5
          short8, make_uint4(pack2(sv[1][4], sv[1][5]), pack2(cv[1][0], cv[1][1]),
                             pack2(cv[1][2], cv[1][3]), pack2(cv[1][4], cv[1][5])));
      hf[4] = __builtin_bit_cast(  // e 32..35: d2 c2-5, then pad
          short8, make_uint4(pack2(cv[2][2], cv[2][3]), pack2(cv[2][4], cv[2][5]), 0u, 0u));
    } else {
      hf[2] = __builtin_bit_cast(  // e 8..15: d0 c2-5, d1 s0-3
          short8, make_uint4(pack2(cv[0][2], cv[0][3]), pack2(cv[0][4], cv[0][5]),
                             pack2(sv[1][0], sv[1][1]), pack2(sv[1][2], sv[1][3])));
      hf[3] = __builtin_bit_cast(  // e 24..31: d2 s0-5, d2 c0-1
          short8, make_uint4(pack2(sv[2][0], sv[2][1]), pack2(sv[2][2], sv[2][3]),
                             pack2(sv[2][4], sv[2][5]), pack2(cv[2][0], cv[2][1])));
      hf[4] = __builtin_bit_cast(short8, make_uint4(0u, 0u, 0u, 0u));
    }
  }

  // ---- phase 2: MLP; weights staged per layer into shared wbuf ----
  short8 bf[8];
  __syncthreads();  // wbuf(layer0) ready
  layer_dense<0, 5>(hf, bf, wbuf, bpack, L, kh);
  __syncthreads(); stage<32>(wpack + (size_t)20 * 512, wbuf, t); __syncthreads();
  layer_dense<1, 8>(bf, bf, wbuf, bpack, L, kh);
  __syncthreads(); stage<32>(wpack + (size_t)52 * 512, wbuf, t); __syncthreads();
  layer_dense<2, 8>(bf, bf, wbuf, bpack, L, kh);
  __syncthreads(); stage<20>(wpack + (size_t)84 * 512, wbuf, t); __syncthreads();
  layer_skip<3, 5>(hf, bf, wbuf, bpack, L, kh);
  __syncthreads(); stage<32>(wpack + (size_t)104 * 512, wbuf, t); __syncthreads();
  layer_dense<4, 8>(bf, bf, wbuf, bpack, L, kh);
  __syncthreads(); stage<32>(wpack + (size_t)136 * 512, wbuf, t); __syncthreads();
  layer_dense<5, 8>(bf, bf, wbuf, bpack, L, kh);
  __syncthreads(); stage<8>(wpack + (size_t)168 * 512, wbuf, t); __syncthreads();

  // ---- output layer: w_out padded to 32x128, only rows 0..3 real ----
  {
    floatx16 a;
    const float4* bp = (const float4*)(bpack + 768 + kh * 16);
#pragma unroll
    for (int g = 0; g < 4; ++g) {
      float4 v = bp[g];
      a[4 * g + 0] = v.x; a[4 * g + 1] = v.y; a[4 * g + 2] = v.z; a[4 * g + 3] = v.w;
    }
    const uint16_t* wp = wbuf + L * 8;
#pragma unroll
    for (int k = 0; k < 8; ++k) {
      short8 af = *(const short8*)(wp + (size_t)k * 512);
      a = __builtin_amdgcn_mfma_f32_32x32x16_bf16(af, bf[k], a, 0, 0, 0);
    }
    if (kh == 0) {  // regs 0..3 = out features 0..3 for point pg
      const float l2e = 1.44269504f;
      float r0 = 1.0f / (1.0f + exp2f(-l2e * a[0]));
      float r1 = 1.0f / (1.0f + exp2f(-l2e * a[1]));
      float r2 = 1.0f / (1.0f + exp2f(-l2e * a[2]));
      float dens = exp2f((a[3] - 1.0f) * l2e) * (sel ? 1.0f : 0.0f);
      dout[pg * 3 + 0] = r0;
      dout[pg * 3 + 1] = r1;
      dout[pg * 3 + 2] = r2;
      dout[RGB_OFF + pg] = dens;
    }
  }
}

extern "C" void kernel_launch(void* const* d_in, const int* in_sizes, int n_in,
                              void* d_out, int out_size, void* d_ws, size_t ws_size,
                              hipStream_t stream) {
  const float* tri = (const float*)d_in[0];
  const float* coords = (const float*)d_in[1];
  const float* w_in = (const float*)d_in[2];
  const float* b_in = (const float*)d_in[3];
  const float* w_skip = (const float*)d_in[4];
  const float* b_skip = (const float*)d_in[5];
  const float* w_bef = (const float*)d_in[6];
  const float* b_bef = (const float*)d_in[7];
  const float* w_aft = (const float*)d_in[8];
  const float* b_aft = (const float*)d_in[9];
  const float* w_out = (const float*)d_in[10];
  const float* b_out = (const float*)d_in[11];
  const size_t TRI_B = (size_t)12 * 256 * 256 * 32 * 2;  // 50,331,648
  const size_t WP_B = (size_t)176 * 1024;                // 180,224
  const size_t BP_B = 3200;
  char* ws = (char*)d_ws;
  const int fast = (ws_size >= TRI_B + WP_B + BP_B) ? 1 : 0;
  uint16_t* trit;
  uint16_t* wpk;
  float* bpk;
  if (fast) {
    trit = (uint16_t*)ws;
    wpk = (uint16_t*)(ws + TRI_B);
    bpk = (float*)(ws + TRI_B + WP_B);
  } else {
    trit = (uint16_t*)ws;  // unused
    wpk = (uint16_t*)ws;
    bpk = (float*)(ws + WP_B);
  }
  if (fast) k_tr<<<dim3(3072), dim3(256), 0, stream>>>(tri, trit);
  k_pack<<<dim3(45), dim3(256), 0, stream>>>(w_in, w_skip, w_bef, w_aft, w_out,
                                             b_in, b_skip, b_bef, b_aft, b_out,
                                             wpk, bpk);
  k_main<<<dim3(2048), dim3(256), 0, stream>>>(trit, tri, coords, wpk, bpk,
                                               (float*)d_out, fast);
}

// Round 11
// 245.125 us; speedup vs baseline: 1.0997x; 1.0997x over previous
//
#include <hip/hip_runtime.h>
#include <stdint.h>

typedef short short8 __attribute__((ext_vector_type(8)));
typedef float floatx16 __attribute__((ext_vector_type(16)));
typedef unsigned int uint32;

#define NPTS (4 * 65536)
#define RGB_OFF (NPTS * 3)

typedef __attribute__((address_space(1))) void GV;
typedef __attribute__((address_space(3))) void LV;

// ---------- helpers ----------
__device__ __forceinline__ uint16_t bf_rne(float f) {
  uint32 u = __float_as_uint(f);
  u += 0x7FFFu + ((u >> 16) & 1u);
  return (uint16_t)(u >> 16);
}
// pack two f32 -> two bf16 (round-half-up) via v_perm_b32
__device__ __forceinline__ uint32 pack2(float a, float b) {
  return __builtin_amdgcn_perm(__float_as_uint(b) + 0x8000u,
                               __float_as_uint(a) + 0x8000u, 0x07060302u);
}
__device__ __forceinline__ float bf_lo(uint32 u) { return __uint_as_float(u << 16); }
__device__ __forceinline__ float bf_hi(uint32 u) { return __uint_as_float(u & 0xFFFF0000u); }
// exchange: a's upper 32 lanes <-> b's lower 32 lanes
__device__ __forceinline__ void swap32(uint32& a, uint32& b) {
  asm("v_permlane32_swap_b32 %0, %1" : "+v"(a), "+v"(b));
}
__device__ __forceinline__ void gacc(const uint16_t* p, float w, float* acc) {
  uint4 q = *(const uint4*)p;
  acc[0] += w * bf_lo(q.x);
  acc[1] += w * bf_hi(q.x);
  acc[2] += w * bf_lo(q.y);
  acc[3] += w * bf_hi(q.y);
  acc[4] += w * bf_lo(q.z);
  acc[5] += w * bf_hi(q.z);
  acc[6] += w * bf_lo(q.w);
  acc[7] += w * bf_hi(q.w);
}

// ---------- kernel 1: triplane (12,32,256,256) f32 -> (12,256,256,32) bf16 ----------
__global__ __launch_bounds__(256) void k_tr(const float* __restrict__ tri,
                                            uint16_t* __restrict__ out) {
  const size_t P = (size_t)blockIdx.x * 256 + threadIdx.x;  // pixel 0..786431
  const int n = (int)(P >> 16);
  const int rem = (int)(P & 65535);
  const float* src = tri + ((size_t)n << 21) + rem;
  uint32 q[16];
#pragma unroll
  for (int c = 0; c < 16; ++c) {
    float a = src[(size_t)(2 * c) << 16];
    float b = src[(size_t)(2 * c + 1) << 16];
    q[c] = pack2(a, b);
  }
  uint4* dst = (uint4*)(out + P * 32);
  dst[0] = make_uint4(q[0], q[1], q[2], q[3]);
  dst[1] = make_uint4(q[4], q[5], q[6], q[7]);
  dst[2] = make_uint4(q[8], q[9], q[10], q[11]);
  dst[3] = make_uint4(q[12], q[13], q[14], q[15]);
}

// ---------- kernel 2: pack weights into half-layer slabs + biases ----------
// wpack layout (uint16 units), 14 half-layer slabs, contiguous:
//  H  lay half  frags  base
//  0   0   0    12     0
//  1   0   1     8     6144
//  2   1   0    16     10240
//  3   1   1    16     18432
//  4   2   0    16     26624
//  5   2   1    16     34816
//  6   3   0    12     43008
//  7   3   1     8     49152
//  8   4   0    16     53248
//  9   4   1    16     61440
// 10   5   0    16     69632
// 11   5   1    16     77824
// 12   6   0     4     86016
// 13   6   1     4     88064   (total 90112 u16 = 180224 B, same as before)
// within a half: frag local index = mt*KsH + kk; frag = 512 u16 (lane L holds 8).
__global__ __launch_bounds__(256) void k_pack(
    const float* __restrict__ w_in, const float* __restrict__ w_skip,
    const float* __restrict__ w_before, const float* __restrict__ w_after,
    const float* __restrict__ w_out, const float* __restrict__ b_in,
    const float* __restrict__ b_skip, const float* __restrict__ b_before,
    const float* __restrict__ b_after, const float* __restrict__ b_out,
    uint16_t* __restrict__ wpack, float* __restrict__ bpack) {
  const int blk = blockIdx.x;
  if (blk >= 44) {  // bias pack: bpack[l*128 + mt*32 + half*16 + reg]
    for (int t = threadIdx.x; t < 800; t += 256) {
      int l, idx;
      if (t < 768) { l = t >> 7; idx = t & 127; }
      else { l = 6; idx = t - 768; }
      int mt = idx >> 5, rem = idx & 31;
      int half = rem >> 4, r = rem & 15;
      int f = mt * 32 + (r & 3) + 8 * (r >> 2) + 4 * half;
      float v;
      switch (l) {
        case 0: v = b_in[f]; break;
        case 1: v = b_before[f]; break;
        case 2: v = b_before[128 + f]; break;
        case 3: v = b_skip[f]; break;
        case 4: v = b_after[f]; break;
        case 5: v = b_after[128 + f]; break;
        default: v = (f < 4) ? b_out[f] : 0.0f; break;
      }
      bpack[l * 128 + idx] = v;
    }
    return;
  }
  const int w = blk * 4 + (threadIdx.x >> 6);  // 0..175
  const int L = threadIdx.x & 63;
  int lay, mt, k;
  if (w < 20)      { lay = 0; mt = w / 5;        k = w - mt * 5; }
  else if (w < 52) { int u = w - 20;  lay = 1; mt = u >> 3; k = u & 7; }
  else if (w < 84) { int u = w - 52;  lay = 2; mt = u >> 3; k = u & 7; }
  else if (w < 104){ int u = w - 84;  lay = 3; mt = u / 5;  k = u - mt * 5; }
  else if (w < 136){ int u = w - 104; lay = 4; mt = u >> 3; k = u & 7; }
  else if (w < 168){ int u = w - 136; lay = 5; mt = u >> 3; k = u & 7; }
  else             { lay = 6; mt = 0; k = w - 168; }
  const float* W;
  int insk = 0;
  switch (lay) {
    case 0: W = w_in; insk = 1; break;
    case 1: W = w_before; break;
    case 2: W = w_before + 16384; break;
    case 3: W = w_skip; insk = 1; break;
    case 4: W = w_after; break;
    case 5: W = w_after + 16384; break;
    default: W = w_out; break;
  }
  const int frow = mt * 32 + (L & 31);
  const int kbase = k * 16 + (L >> 5) * 8;
  uint16_t h[8];
#pragma unroll
  for (int j = 0; j < 8; ++j) {
    int kl = kbase + j;
    float v;
    if (insk) {
      int col = (kl < 32) ? (36 + kl) : ((kl < 68) ? (kl - 32) : -1);
      v = (col < 0) ? 0.0f : W[frow * 68 + col];
    } else if (lay == 6) {
      v = (frow < 4) ? W[frow * 128 + kl] : 0.0f;
    } else {
      v = W[frow * 128 + kl];
    }
    h[j] = bf_rne(v);
  }
  uint4 q;
  q.x = (uint32)h[0] | ((uint32)h[1] << 16);
  q.y = (uint32)h[2] | ((uint32)h[3] << 16);
  q.z = (uint32)h[4] | ((uint32)h[5] << 16);
  q.w = (uint32)h[6] | ((uint32)h[7] << 16);
  // half-slab destination offset
  int LBASE;
  switch (lay) {
    case 0: LBASE = 0; break;
    case 1: LBASE = 10240; break;
    case 2: LBASE = 26624; break;
    case 3: LBASE = 43008; break;
    case 4: LBASE = 53248; break;
    case 5: LBASE = 69632; break;
    default: LBASE = 86016; break;
  }
  const int kh0 = insk ? 3 : 4;
  const int ksTot = insk ? 5 : 8;
  const int hh = (k >= kh0) ? 1 : 0;
  const int ksh = hh ? (ksTot - kh0) : kh0;
  const int kk = k - hh * kh0;
  const int h0frags = (lay == 6) ? 4 : kh0 * 4;
  const size_t off = (size_t)LBASE + (size_t)(hh ? h0frags * 512 : 0) +
                     (size_t)(mt * ksh + kk) * 512 + (size_t)L * 8;
  *(uint4*)(wpack + off) = q;
}

// ---------- async weight staging: global -> LDS via DMA, no VGPR round trip ----------
// CH 16B-chunks per thread; per-wave LDS dest is linear (uniform base + lane*16).
template <int CH>
__device__ __forceinline__ void stageA(const uint16_t* __restrict__ gp,
                                       uint16_t* __restrict__ lp, int t) {
#pragma unroll
  for (int i = 0; i < CH; ++i) {
    const int g = (t + i * 256) * 8;
    __builtin_amdgcn_global_load_lds((GV*)(gp + g), (LV*)(lp + g), 16, 0, 0);
  }
  __builtin_amdgcn_sched_barrier(0);  // pin DMA issue point
}

// counted-vmcnt barrier: wait until <=N VMEM ops outstanding AND all of this
// wave's LDS reads complete (lgkmcnt(0)), then block barrier.
// The lgkm drain closes the race where a slot's ds_reads are still pending
// when another wave (post-barrier) issues the DMA that overwrites the slot:
// global_load_lds' LDS-write is vmcnt-domain and unordered vs pending DS ops.
template <int N>
__device__ __forceinline__ void bar_keep() {
  asm volatile("s_waitcnt vmcnt(%0) lgkmcnt(0)" :: "i"(N) : "memory");
  __builtin_amdgcn_s_barrier();
  asm volatile("" ::: "memory");
}

// ---------- register-resident MLP machinery ----------
__device__ __forceinline__ void acc_init4(floatx16* a, const float* bl, int LAY,
                                          int kh) {
#pragma unroll
  for (int mt = 0; mt < 4; ++mt) {
    const float4* bp = (const float4*)(bl + LAY * 128 + mt * 32 + kh * 16);
#pragma unroll
    for (int g = 0; g < 4; ++g) {
      float4 v = bp[g];
      a[mt][4 * g + 0] = v.x; a[mt][4 * g + 1] = v.y;
      a[mt][4 * g + 2] = v.z; a[mt][4 * g + 3] = v.w;
    }
  }
}

// one K-chunk of a layer: KsH k-steps; frags laid out (mt*KsH + k)*512 in slot wb
template <int KsH>
__device__ __forceinline__ void chunk4(floatx16* a, const short8* bin,
                                       const uint16_t* __restrict__ wb, int L) {
  const uint16_t* wp = wb + L * 8;
#pragma unroll
  for (int k = 0; k < KsH; ++k) {
    short8 w0 = *(const short8*)(wp + (size_t)(0 * KsH + k) * 512);
    short8 w1 = *(const short8*)(wp + (size_t)(1 * KsH + k) * 512);
    short8 w2 = *(const short8*)(wp + (size_t)(2 * KsH + k) * 512);
    short8 w3 = *(const short8*)(wp + (size_t)(3 * KsH + k) * 512);
    a[0] = __builtin_amdgcn_mfma_f32_32x32x16_bf16(w0, bin[k], a[0], 0, 0, 0);
    a[1] = __builtin_amdgcn_mfma_f32_32x32x16_bf16(w1, bin[k], a[1], 0, 0, 0);
    a[2] = __builtin_amdgcn_mfma_f32_32x32x16_bf16(w2, bin[k], a[2], 0, 0, 0);
    a[3] = __builtin_amdgcn_mfma_f32_32x32x16_bf16(w3, bin[k], a[3], 0, 0, 0);
  }
}

__device__ __forceinline__ void epi_dense(const floatx16* a, short8* bout) {
#pragma unroll
  for (int f = 0; f < 8; ++f) {
    const int mt = f >> 1, s = f & 1;
    uint32 q0a = pack2(fmaxf(a[mt][8 * s + 0], 0.f), fmaxf(a[mt][8 * s + 1], 0.f));
    uint32 q0b = pack2(fmaxf(a[mt][8 * s + 2], 0.f), fmaxf(a[mt][8 * s + 3], 0.f));
    uint32 q1a = pack2(fmaxf(a[mt][8 * s + 4], 0.f), fmaxf(a[mt][8 * s + 5], 0.f));
    uint32 q1b = pack2(fmaxf(a[mt][8 * s + 6], 0.f), fmaxf(a[mt][8 * s + 7], 0.f));
    swap32(q0a, q1a);
    swap32(q0b, q1b);
    bout[f] = __builtin_bit_cast(short8, make_uint4(q0a, q0b, q1a, q1b));
  }
}

__device__ __forceinline__ void epi_skip(const floatx16* a, short8* bio) {
#pragma unroll
  for (int f = 0; f < 8; ++f) {
    const int mt = f >> 1, s = f & 1;
    uint4 old = __builtin_bit_cast(uint4, bio[f]);
    uint32 uA = old.x, uB = old.y, uC = old.z, uD = old.w;
    swap32(uA, uC);  // involution: back to C-layout packed x2
    swap32(uB, uD);
    float r0 = fmaxf(a[mt][8 * s + 0], 0.f) + bf_lo(uA);
    float r1 = fmaxf(a[mt][8 * s + 1], 0.f) + bf_hi(uA);
    float r2 = fmaxf(a[mt][8 * s + 2], 0.f) + bf_lo(uB);
    float r3 = fmaxf(a[mt][8 * s + 3], 0.f) + bf_hi(uB);
    float r4 = fmaxf(a[mt][8 * s + 4], 0.f) + bf_lo(uC);
    float r5 = fmaxf(a[mt][8 * s + 5], 0.f) + bf_hi(uC);
    float r6 = fmaxf(a[mt][8 * s + 6], 0.f) + bf_lo(uD);
    float r7 = fmaxf(a[mt][8 * s + 7], 0.f) + bf_hi(uD);
    uint32 q0a = pack2(r0, r1), q0b = pack2(r2, r3);
    uint32 q1a = pack2(r4, r5), q1b = pack2(r6, r7);
    swap32(q0a, q1a);
    swap32(q0b, q1b);
    bio[f] = __builtin_bit_cast(short8, make_uint4(q0a, q0b, q1a, q1b));
  }
}

// ---------- kernel 3: fused gather + encode + MLP ----------
// Wave owns 32 points; activations register-resident; weights DMA-staged 3 half-
// layers ahead into a 16KB x 3 LDS ring (pipelined; never drained mid-loop).
__global__ __launch_bounds__(256, 3) void k_main(
    const uint16_t* __restrict__ trit, const float* __restrict__ trif,
    const float* __restrict__ coords, const uint16_t* __restrict__ wpack,
    const float* __restrict__ bpack, float* __restrict__ dout, int fast) {
  __shared__ __align__(16) uint16_t ring[3][8192];  // 48KB: 3 half-layer slots
  __shared__ __align__(16) float blds[800];         // 3.2KB: all biases
  const int t = threadIdx.x;
  const int L = t & 63;
  const int kh = L >> 5;
  const int p = (t >> 6) * 32 + (L & 31);
  const int pg = blockIdx.x * 128 + p;

  // issue prologue DMA early: halves H0,H1,H2 -> slots 0,1,2 (overlap gather)
  stageA<3>(wpack + 0,     ring[0], t);   // H0: L0 k0-2 (12KB)
  stageA<2>(wpack + 6144,  ring[1], t);   // H1: L0 k3-4 (8KB)
  stageA<4>(wpack + 10240, ring[2], t);   // H2: L1 k0-3 (16KB)
  // all 800 bias floats -> LDS (400 float2, strided over 256 threads)
  for (int i = t; i < 400; i += 256)
    ((float2*)blds)[i] = ((const float2*)bpack)[i];

  // ---- phase 1: gather + freq encode, directly into B-frag registers ----
  float cx = coords[pg * 3 + 0], cy = coords[pg * 3 + 1], cz = coords[pg * 3 + 2];
  float f1x = cx + 1.0f, f1y = cy + 1.0f, f1z = cz + 1.0f;
  float nx = f1x * 0.5f, ny = f1y * 0.5f, nz = f1z * 0.5f;
  float sx = f1x - 1.0f, sy = f1y - 1.0f, sz = f1z - 1.0f;
  bool sel = (nx > 0.f) & (nx < 1.f) & (ny > 0.f) & (ny < 1.f) & (nz > 0.f) & (nz < 1.f);
  const int b = pg >> 16;
  float acc[16];
#pragma unroll
  for (int j = 0; j < 16; ++j) acc[j] = 0.f;
#pragma unroll
  for (int pl = 0; pl < 3; ++pl) {
    float gx = (pl == 2) ? sy : sx;
    float gy = (pl == 0) ? sy : sz;
    float ix = ((gx + 1.0f) * 0.5f) * 255.0f;
    float iy = ((gy + 1.0f) * 0.5f) * 255.0f;
    float x0f = floorf(ix), y0f = floorf(iy);
    float wx = ix - x0f, wy = iy - y0f;
    float vx0 = (x0f >= 0.0f && x0f < 256.0f) ? 1.f : 0.f;
    float vx1 = (x0f >= -1.0f && x0f < 255.0f) ? 1.f : 0.f;
    float vy0 = (y0f >= 0.0f && y0f < 256.0f) ? 1.f : 0.f;
    float vy1 = (y0f >= -1.0f && y0f < 255.0f) ? 1.f : 0.f;
    int x0 = min(max((int)x0f, 0), 255), x1 = min(max((int)x0f + 1, 0), 255);
    int y0 = min(max((int)y0f, 0), 255), y1 = min(max((int)y0f + 1, 0), 255);
    float w00 = (1.f - wx) * (1.f - wy) * vx0 * vy0;
    float w10 = wx * (1.f - wy) * vx1 * vy0;
    float w01 = (1.f - wx) * wy * vx0 * vy1;
    float w11 = wx * wy * vx1 * vy1;
    const int n = 3 * b + pl;
    if (fast) {
      // lane's channel chunks: [kh*8, kh*8+8) and [16+kh*8, ...)
      const uint16_t* cb = trit + ((size_t)n << 21) + kh * 8;
      size_t o00 = (size_t)(y0 * 256 + x0) << 5, o10 = (size_t)(y0 * 256 + x1) << 5;
      size_t o01 = (size_t)(y1 * 256 + x0) << 5, o11 = (size_t)(y1 * 256 + x1) << 5;
      gacc(cb + o00, w00, acc); gacc(cb + 16 + o00, w00, acc + 8);
      gacc(cb + o10, w10, acc); gacc(cb + 16 + o10, w10, acc + 8);
      gacc(cb + o01, w01, acc); gacc(cb + 16 + o01, w01, acc + 8);
      gacc(cb + o11, w11, acc); gacc(cb + 16 + o11, w11, acc + 8);
    } else {
      const float* basef = trif + (((size_t)n * 32) << 16);
#pragma unroll
      for (int j = 0; j < 8; ++j) {
        const float* c0p = basef + (((size_t)(kh * 8 + j)) << 16);
        const float* c1p = basef + (((size_t)(16 + kh * 8 + j)) << 16);
        acc[j] += w00 * c0p[y0 * 256 + x0] + w10 * c0p[y0 * 256 + x1] +
                  w01 * c0p[y1 * 256 + x0] + w11 * c0p[y1 * 256 + x1];
        acc[8 + j] += w00 * c1p[y0 * 256 + x0] + w10 * c1p[y0 * 256 + x1] +
                      w01 * c1p[y1 * 256 + x0] + w11 * c1p[y1 * 256 + x1];
      }
    }
  }
  short8 hf[5];
  hf[0] = __builtin_bit_cast(
      short8, make_uint4(pack2(acc[0], acc[1]), pack2(acc[2], acc[3]),
                         pack2(acc[4], acc[5]), pack2(acc[6], acc[7])));
  hf[1] = __builtin_bit_cast(
      short8, make_uint4(pack2(acc[8], acc[9]), pack2(acc[10], acc[11]),
                         pack2(acc[12], acc[13]), pack2(acc[14], acc[15])));
  {
    // freq cols 32+e, e = d*12 + (sin: k | cos: 6+k)
    float sv[3][6], cv[3][6];
#pragma unroll
    for (int d = 0; d < 3; ++d) {
      float nd = (d == 0) ? nx : (d == 1) ? ny : nz;
#pragma unroll
      for (int k = 0; k < 6; ++k) {
        float rev = nd * (0.5f * (float)(1 << k));
        float r = rev - rintf(rev);
        sv[d][k] = __builtin_amdgcn_sinf(r);
        cv[d][k] = __builtin_amdgcn_cosf(r);
      }
    }
    if (kh == 0) {
      hf[2] = __builtin_bit_cast(  // e 0..7: d0 s0-5, d0 c0-1
          short8, make_uint4(pack2(sv[0][0], sv[0][1]), pack2(sv[0][2], sv[0][3]),
                             pack2(sv[0][4], sv[0][5]), pack2(cv[0][0], cv[0][1])));
      hf[3] = __builtin_bit_cast(  // e 16..23: d1 s4-5, d1 c0-5
          short8, make_uint4(pack2(sv[1][4], sv[1][5]), pack2(cv[1][0], cv[1][1]),
                             pack2(cv[1][2], cv[1][3]), pack2(cv[1][4], cv[1][5])));
      hf[4] = __builtin_bit_cast(  // e 32..35: d2 c2-5, then pad
          short8, make_uint4(pack2(cv[2][2], cv[2][3]), pack2(cv[2][4], cv[2][5]), 0u, 0u));
    } else {
      hf[2] = __builtin_bit_cast(  // e 8..15: d0 c2-5, d1 s0-3
          short8, make_uint4(pack2(cv[0][2], cv[0][3]), pack2(cv[0][4], cv[0][5]),
                             pack2(sv[1][0], sv[1][1]), pack2(sv[1][2], sv[1][3])));
      hf[3] = __builtin_bit_cast(  // e 24..31: d2 s0-5, d2 c0-1
          short8, make_uint4(pack2(sv[2][0], sv[2][1]), pack2(sv[2][2], sv[2][3]),
                             pack2(sv[2][4], sv[2][5]), pack2(cv[2][0], cv[2][1])));
      hf[4] = __builtin_bit_cast(short8, make_uint4(0u, 0u, 0u, 0u));
    }
  }

  // ---- phase 2: MLP; half-layer ring pipeline, stages issued 3 halves ahead ----
  __syncthreads();  // drains prologue DMA (H0-H2), bias copy, gather loads
  floatx16 a[4];
  short8 bf[8];

  // L0 (Ks 3+2)
  acc_init4(a, blds, 0, kh);
  chunk4<3>(a, hf, ring[0], L);                       // H0
  bar_keep<0>(); stageA<4>(wpack + 18432, ring[0], t);  // H3
  chunk4<2>(a, hf + 3, ring[1], L);                   // H1
  bar_keep<4>(); stageA<4>(wpack + 26624, ring[1], t);  // H4
  epi_dense(a, bf);

  // L1 (4+4)
  acc_init4(a, blds, 1, kh);
  chunk4<4>(a, bf, ring[2], L);                       // H2
  bar_keep<4>(); stageA<4>(wpack + 34816, ring[2], t);  // H5
  chunk4<4>(a, bf + 4, ring[0], L);                   // H3
  bar_keep<4>(); stageA<3>(wpack + 43008, ring[0], t);  // H6
  epi_dense(a, bf);

  // L2 (4+4)
  acc_init4(a, blds, 2, kh);
  chunk4<4>(a, bf, ring[1], L);                       // H4
  bar_keep<3>(); stageA<2>(wpack + 49152, ring[1], t);  // H7
  chunk4<4>(a, bf + 4, ring[2], L);                   // H5
  bar_keep<2>(); stageA<4>(wpack + 53248, ring[2], t);  // H8
  epi_dense(a, bf);

  // L3 skip (3+2)
  acc_init4(a, blds, 3, kh);
  chunk4<3>(a, hf, ring[0], L);                       // H6
  bar_keep<4>(); stageA<4>(wpack + 61440, ring[0], t);  // H9
  chunk4<2>(a, hf + 3, ring[1], L);                   // H7
  bar_keep<4>(); stageA<4>(wpack + 69632, ring[1], t);  // H10
  epi_skip(a, bf);

  // L4 (4+4)
  acc_init4(a, blds, 4, kh);
  chunk4<4>(a, bf, ring[2], L);                       // H8
  bar_keep<4>(); stageA<4>(wpack + 77824, ring[2], t);  // H11
  chunk4<4>(a, bf + 4, ring[0], L);                   // H9
  bar_keep<4>(); stageA<1>(wpack + 86016, ring[0], t);  // H12
  epi_dense(a, bf);

  // L5 (4+4)
  acc_init4(a, blds, 5, kh);
  chunk4<4>(a, bf, ring[1], L);                       // H10
  bar_keep<1>(); stageA<1>(wpack + 88064, ring[1], t);  // H13
  chunk4<4>(a, bf + 4, ring[2], L);                   // H11
  bar_keep<1>();
  epi_dense(a, bf);

  // ---- output layer: w_out padded to 32x128, only rows 0..3 real ----
  {
    floatx16 ao;
    const float4* bp = (const float4*)(blds + 768 + kh * 16);
#pragma unroll
    for (int g = 0; g < 4; ++g) {
      float4 v = bp[g];
      ao[4 * g + 0] = v.x; ao[4 * g + 1] = v.y; ao[4 * g + 2] = v.z; ao[4 * g + 3] = v.w;
    }
    {
      const uint16_t* wp = ring[0] + L * 8;                // H12: k0-3
#pragma unroll
      for (int k = 0; k < 4; ++k) {
        short8 af = *(const short8*)(wp + (size_t)k * 512);
        ao = __builtin_amdgcn_mfma_f32_32x32x16_bf16(af, bf[k], ao, 0, 0, 0);
      }
    }
    bar_keep<0>();  // H13 staged by all waves, drained
    {
      const uint16_t* wp = ring[1] + L * 8;                // H13: k4-7
#pragma unroll
      for (int k = 0; k < 4; ++k) {
        short8 af = *(const short8*)(wp + (size_t)k * 512);
        ao = __builtin_amdgcn_mfma_f32_32x32x16_bf16(af, bf[4 + k], ao, 0, 0, 0);
      }
    }
    if (kh == 0) {  // regs 0..3 = out features 0..3 for point pg
      const float l2e = 1.44269504f;
      float r0 = 1.0f / (1.0f + exp2f(-l2e * ao[0]));
      float r1 = 1.0f / (1.0f + exp2f(-l2e * ao[1]));
      float r2 = 1.0f / (1.0f + exp2f(-l2e * ao[2]));
      float dens = exp2f((ao[3] - 1.0f) * l2e) * (sel ? 1.0f : 0.0f);
      dout[pg * 3 + 0] = r0;
      dout[pg * 3 + 1] = r1;
      dout[pg * 3 + 2] = r2;
      dout[RGB_OFF + pg] = dens;
    }
  }
}

extern "C" void kernel_launch(void* const* d_in, const int* in_sizes, int n_in,
                              void* d_out, int out_size, void* d_ws, size_t ws_size,
                              hipStream_t stream) {
  const float* tri = (const float*)d_in[0];
  const float* coords = (const float*)d_in[1];
  const float* w_in = (const float*)d_in[2];
  const float* b_in = (const float*)d_in[3];
  const float* w_skip = (const float*)d_in[4];
  const float* b_skip = (const float*)d_in[5];
  const float* w_bef = (const float*)d_in[6];
  const float* b_bef = (const float*)d_in[7];
  const float* w_aft = (const float*)d_in[8];
  const float* b_aft = (const float*)d_in[9];
  const float* w_out = (const float*)d_in[10];
  const float* b_out = (const float*)d_in[11];
  const size_t TRI_B = (size_t)12 * 256 * 256 * 32 * 2;  // 50,331,648
  const size_t WP_B = (size_t)176 * 1024;                // 180,224 (unchanged)
  const size_t BP_B = 3200;
  char* ws = (char*)d_ws;
  const int fast = (ws_size >= TRI_B + WP_B + BP_B) ? 1 : 0;
  uint16_t* trit;
  uint16_t* wpk;
  float* bpk;
  if (fast) {
    trit = (uint16_t*)ws;
    wpk = (uint16_t*)(ws + TRI_B);
    bpk = (float*)(ws + TRI_B + WP_B);
  } else {
    trit = (uint16_t*)ws;  // unused
    wpk = (uint16_t*)ws;
    bpk = (float*)(ws + WP_B);
  }
  if (fast) k_tr<<<dim3(3072), dim3(256), 0, stream>>>(tri, trit);
  k_pack<<<dim3(45), dim3(256), 0, stream>>>(w_in, w_skip, w_bef, w_aft, w_out,
                                             b_in, b_skip, b_bef, b_aft, b_out,
                                             wpk, bpk);
  k_main<<<dim3(2048), dim3(256), 0, stream>>>(trit, tri, coords, wpk, bpk,
                                               (float*)d_out, fast);
}

// Round 12
// 244.182 us; speedup vs baseline: 1.1039x; 1.0039x over previous
//
#include <hip/hip_runtime.h>
#include <stdint.h>

typedef short short8 __attribute__((ext_vector_type(8)));
typedef float floatx16 __attribute__((ext_vector_type(16)));
typedef unsigned int uint32;

#define NPTS (4 * 65536)
#define RGB_OFF (NPTS * 3)

typedef __attribute__((address_space(1))) void GV;
typedef __attribute__((address_space(3))) void LV;

// ---------- helpers ----------
__device__ __forceinline__ uint16_t bf_rne(float f) {
  uint32 u = __float_as_uint(f);
  u += 0x7FFFu + ((u >> 16) & 1u);
  return (uint16_t)(u >> 16);
}
// pack two f32 -> two bf16 (RNE) in ONE VALU op via v_cvt_pk_bf16_f32.
// dst.lo = bf16(a), dst.hi = bf16(b) — same layout as the old add+perm pack2.
// Non-volatile pure-VALU asm: scheduler/CSE remain free to optimize.
__device__ __forceinline__ uint32 pack2(float a, float b) {
  uint32 r;
  asm("v_cvt_pk_bf16_f32 %0, %1, %2" : "=v"(r) : "v"(a), "v"(b));
  return r;
}
__device__ __forceinline__ float bf_lo(uint32 u) { return __uint_as_float(u << 16); }
__device__ __forceinline__ float bf_hi(uint32 u) { return __uint_as_float(u & 0xFFFF0000u); }
// exchange: a's upper 32 lanes <-> b's lower 32 lanes
__device__ __forceinline__ void swap32(uint32& a, uint32& b) {
  asm("v_permlane32_swap_b32 %0, %1" : "+v"(a), "+v"(b));
}
__device__ __forceinline__ void gacc(const uint16_t* p, float w, float* acc) {
  uint4 q = *(const uint4*)p;
  acc[0] += w * bf_lo(q.x);
  acc[1] += w * bf_hi(q.x);
  acc[2] += w * bf_lo(q.y);
  acc[3] += w * bf_hi(q.y);
  acc[4] += w * bf_lo(q.z);
  acc[5] += w * bf_hi(q.z);
  acc[6] += w * bf_lo(q.w);
  acc[7] += w * bf_hi(q.w);
}

// ---------- kernel 1: triplane (12,32,256,256) f32 -> (12,256,256,32) bf16 ----------
__global__ __launch_bounds__(256) void k_tr(const float* __restrict__ tri,
                                            uint16_t* __restrict__ out) {
  const size_t P = (size_t)blockIdx.x * 256 + threadIdx.x;  // pixel 0..786431
  const int n = (int)(P >> 16);
  const int rem = (int)(P & 65535);
  const float* src = tri + ((size_t)n << 21) + rem;
  uint32 q[16];
#pragma unroll
  for (int c = 0; c < 16; ++c) {
    float a = src[(size_t)(2 * c) << 16];
    float b = src[(size_t)(2 * c + 1) << 16];
    q[c] = pack2(a, b);
  }
  uint4* dst = (uint4*)(out + P * 32);
  dst[0] = make_uint4(q[0], q[1], q[2], q[3]);
  dst[1] = make_uint4(q[4], q[5], q[6], q[7]);
  dst[2] = make_uint4(q[8], q[9], q[10], q[11]);
  dst[3] = make_uint4(q[12], q[13], q[14], q[15]);
}

// ---------- kernel 2: pack weights into half-layer slabs + biases ----------
// wpack layout (uint16 units), 14 half-layer slabs, contiguous:
//  H  lay half  frags  base
//  0   0   0    12     0
//  1   0   1     8     6144
//  2   1   0    16     10240
//  3   1   1    16     18432
//  4   2   0    16     26624
//  5   2   1    16     34816
//  6   3   0    12     43008
//  7   3   1     8     49152
//  8   4   0    16     53248
//  9   4   1    16     61440
// 10   5   0    16     69632
// 11   5   1    16     77824
// 12   6   0     4     86016
// 13   6   1     4     88064   (total 90112 u16 = 180224 B)
// within a half: frag local index = mt*KsH + kk; frag = 512 u16 (lane L holds 8).
__global__ __launch_bounds__(256) void k_pack(
    const float* __restrict__ w_in, const float* __restrict__ w_skip,
    const float* __restrict__ w_before, const float* __restrict__ w_after,
    const float* __restrict__ w_out, const float* __restrict__ b_in,
    const float* __restrict__ b_skip, const float* __restrict__ b_before,
    const float* __restrict__ b_after, const float* __restrict__ b_out,
    uint16_t* __restrict__ wpack, float* __restrict__ bpack) {
  const int blk = blockIdx.x;
  if (blk >= 44) {  // bias pack: bpack[l*128 + mt*32 + half*16 + reg]
    for (int t = threadIdx.x; t < 800; t += 256) {
      int l, idx;
      if (t < 768) { l = t >> 7; idx = t & 127; }
      else { l = 6; idx = t - 768; }
      int mt = idx >> 5, rem = idx & 31;
      int half = rem >> 4, r = rem & 15;
      int f = mt * 32 + (r & 3) + 8 * (r >> 2) + 4 * half;
      float v;
      switch (l) {
        case 0: v = b_in[f]; break;
        case 1: v = b_before[f]; break;
        case 2: v = b_before[128 + f]; break;
        case 3: v = b_skip[f]; break;
        case 4: v = b_after[f]; break;
        case 5: v = b_after[128 + f]; break;
        default: v = (f < 4) ? b_out[f] : 0.0f; break;
      }
      bpack[l * 128 + idx] = v;
    }
    return;
  }
  const int w = blk * 4 + (threadIdx.x >> 6);  // 0..175
  const int L = threadIdx.x & 63;
  int lay, mt, k;
  if (w < 20)      { lay = 0; mt = w / 5;        k = w - mt * 5; }
  else if (w < 52) { int u = w - 20;  lay = 1; mt = u >> 3; k = u & 7; }
  else if (w < 84) { int u = w - 52;  lay = 2; mt = u >> 3; k = u & 7; }
  else if (w < 104){ int u = w - 84;  lay = 3; mt = u / 5;  k = u - mt * 5; }
  else if (w < 136){ int u = w - 104; lay = 4; mt = u >> 3; k = u & 7; }
  else if (w < 168){ int u = w - 136; lay = 5; mt = u >> 3; k = u & 7; }
  else             { lay = 6; mt = 0; k = w - 168; }
  const float* W;
  int insk = 0;
  switch (lay) {
    case 0: W = w_in; insk = 1; break;
    case 1: W = w_before; break;
    case 2: W = w_before + 16384; break;
    case 3: W = w_skip; insk = 1; break;
    case 4: W = w_after; break;
    case 5: W = w_after + 16384; break;
    default: W = w_out; break;
  }
  const int frow = mt * 32 + (L & 31);
  const int kbase = k * 16 + (L >> 5) * 8;
  uint16_t h[8];
#pragma unroll
  for (int j = 0; j < 8; ++j) {
    int kl = kbase + j;
    float v;
    if (insk) {
      int col = (kl < 32) ? (36 + kl) : ((kl < 68) ? (kl - 32) : -1);
      v = (col < 0) ? 0.0f : W[frow * 68 + col];
    } else if (lay == 6) {
      v = (frow < 4) ? W[frow * 128 + kl] : 0.0f;
    } else {
      v = W[frow * 128 + kl];
    }
    h[j] = bf_rne(v);
  }
  uint4 q;
  q.x = (uint32)h[0] | ((uint32)h[1] << 16);
  q.y = (uint32)h[2] | ((uint32)h[3] << 16);
  q.z = (uint32)h[4] | ((uint32)h[5] << 16);
  q.w = (uint32)h[6] | ((uint32)h[7] << 16);
  // half-slab destination offset
  int LBASE;
  switch (lay) {
    case 0: LBASE = 0; break;
    case 1: LBASE = 10240; break;
    case 2: LBASE = 26624; break;
    case 3: LBASE = 43008; break;
    case 4: LBASE = 53248; break;
    case 5: LBASE = 69632; break;
    default: LBASE = 86016; break;
  }
  const int kh0 = insk ? 3 : 4;
  const int ksTot = insk ? 5 : 8;
  const int hh = (k >= kh0) ? 1 : 0;
  const int ksh = hh ? (ksTot - kh0) : kh0;
  const int kk = k - hh * kh0;
  const int h0frags = (lay == 6) ? 4 : kh0 * 4;
  const size_t off = (size_t)LBASE + (size_t)(hh ? h0frags * 512 : 0) +
                     (size_t)(mt * ksh + kk) * 512 + (size_t)L * 8;
  *(uint4*)(wpack + off) = q;
}

// ---------- async weight staging: global -> LDS via DMA, no VGPR round trip ----------
// CH 16B-chunks per thread; per-wave LDS dest is linear (uniform base + lane*16).
template <int CH>
__device__ __forceinline__ void stageA(const uint16_t* __restrict__ gp,
                                       uint16_t* __restrict__ lp, int t) {
#pragma unroll
  for (int i = 0; i < CH; ++i) {
    const int g = (t + i * 256) * 8;
    __builtin_amdgcn_global_load_lds((GV*)(gp + g), (LV*)(lp + g), 16, 0, 0);
  }
  __builtin_amdgcn_sched_barrier(0);  // pin DMA issue point
}

// counted-vmcnt barrier: wait until <=N VMEM ops outstanding AND all of this
// wave's LDS reads complete (lgkmcnt(0)), then block barrier.
// The lgkm drain closes the race where a slot's ds_reads are still pending
// when another wave (post-barrier) issues the DMA that overwrites the slot:
// global_load_lds' LDS-write is vmcnt-domain and unordered vs pending DS ops.
template <int N>
__device__ __forceinline__ void bar_keep() {
  asm volatile("s_waitcnt vmcnt(%0) lgkmcnt(0)" :: "i"(N) : "memory");
  __builtin_amdgcn_s_barrier();
  asm volatile("" ::: "memory");
}

// ---------- register-resident MLP machinery ----------
__device__ __forceinline__ void acc_init4(floatx16* a, const float* bl, int LAY,
                                          int kh) {
#pragma unroll
  for (int mt = 0; mt < 4; ++mt) {
    const float4* bp = (const float4*)(bl + LAY * 128 + mt * 32 + kh * 16);
#pragma unroll
    for (int g = 0; g < 4; ++g) {
      float4 v = bp[g];
      a[mt][4 * g + 0] = v.x; a[mt][4 * g + 1] = v.y;
      a[mt][4 * g + 2] = v.z; a[mt][4 * g + 3] = v.w;
    }
  }
}

// one K-chunk of a layer: KsH k-steps; frags laid out (mt*KsH + k)*512 in slot wb
template <int KsH>
__device__ __forceinline__ void chunk4(floatx16* a, const short8* bin,
                                       const uint16_t* __restrict__ wb, int L) {
  const uint16_t* wp = wb + L * 8;
#pragma unroll
  for (int k = 0; k < KsH; ++k) {
    short8 w0 = *(const short8*)(wp + (size_t)(0 * KsH + k) * 512);
    short8 w1 = *(const short8*)(wp + (size_t)(1 * KsH + k) * 512);
    short8 w2 = *(const short8*)(wp + (size_t)(2 * KsH + k) * 512);
    short8 w3 = *(const short8*)(wp + (size_t)(3 * KsH + k) * 512);
    a[0] = __builtin_amdgcn_mfma_f32_32x32x16_bf16(w0, bin[k], a[0], 0, 0, 0);
    a[1] = __builtin_amdgcn_mfma_f32_32x32x16_bf16(w1, bin[k], a[1], 0, 0, 0);
    a[2] = __builtin_amdgcn_mfma_f32_32x32x16_bf16(w2, bin[k], a[2], 0, 0, 0);
    a[3] = __builtin_amdgcn_mfma_f32_32x32x16_bf16(w3, bin[k], a[3], 0, 0, 0);
  }
}

__device__ __forceinline__ void epi_dense(const floatx16* a, short8* bout) {
#pragma unroll
  for (int f = 0; f < 8; ++f) {
    const int mt = f >> 1, s = f & 1;
    uint32 q0a = pack2(fmaxf(a[mt][8 * s + 0], 0.f), fmaxf(a[mt][8 * s + 1], 0.f));
    uint32 q0b = pack2(fmaxf(a[mt][8 * s + 2], 0.f), fmaxf(a[mt][8 * s + 3], 0.f));
    uint32 q1a = pack2(fmaxf(a[mt][8 * s + 4], 0.f), fmaxf(a[mt][8 * s + 5], 0.f));
    uint32 q1b = pack2(fmaxf(a[mt][8 * s + 6], 0.f), fmaxf(a[mt][8 * s + 7], 0.f));
    swap32(q0a, q1a);
    swap32(q0b, q1b);
    bout[f] = __builtin_bit_cast(short8, make_uint4(q0a, q0b, q1a, q1b));
  }
}

__device__ __forceinline__ void epi_skip(const floatx16* a, short8* bio) {
#pragma unroll
  for (int f = 0; f < 8; ++f) {
    const int mt = f >> 1, s = f & 1;
    uint4 old = __builtin_bit_cast(uint4, bio[f]);
    uint32 uA = old.x, uB = old.y, uC = old.z, uD = old.w;
    swap32(uA, uC);  // involution: back to C-layout packed x2
    swap32(uB, uD);
    float r0 = fmaxf(a[mt][8 * s + 0], 0.f) + bf_lo(uA);
    float r1 = fmaxf(a[mt][8 * s + 1], 0.f) + bf_hi(uA);
    float r2 = fmaxf(a[mt][8 * s + 2], 0.f) + bf_lo(uB);
    float r3 = fmaxf(a[mt][8 * s + 3], 0.f) + bf_hi(uB);
    float r4 = fmaxf(a[mt][8 * s + 4], 0.f) + bf_lo(uC);
    float r5 = fmaxf(a[mt][8 * s + 5], 0.f) + bf_hi(uC);
    float r6 = fmaxf(a[mt][8 * s + 6], 0.f) + bf_lo(uD);
    float r7 = fmaxf(a[mt][8 * s + 7], 0.f) + bf_hi(uD);
    uint32 q0a = pack2(r0, r1), q0b = pack2(r2, r3);
    uint32 q1a = pack2(r4, r5), q1b = pack2(r6, r7);
    swap32(q0a, q1a);
    swap32(q0b, q1b);
    bio[f] = __builtin_bit_cast(short8, make_uint4(q0a, q0b, q1a, q1b));
  }
}

// ---------- kernel 3: fused gather + encode + MLP ----------
// Wave owns 32 points; activations register-resident; weights DMA-staged 3 half-
// layers ahead into a 16KB x 3 LDS ring (pipelined; never drained mid-loop).
__global__ __launch_bounds__(256, 3) void k_main(
    const uint16_t* __restrict__ trit, const float* __restrict__ trif,
    const float* __restrict__ coords, const uint16_t* __restrict__ wpack,
    const float* __restrict__ bpack, float* __restrict__ dout, int fast) {
  __shared__ __align__(16) uint16_t ring[3][8192];  // 48KB: 3 half-layer slots
  __shared__ __align__(16) float blds[800];         // 3.2KB: all biases
  const int t = threadIdx.x;
  const int L = t & 63;
  const int kh = L >> 5;
  const int p = (t >> 6) * 32 + (L & 31);
  const int pg = blockIdx.x * 128 + p;

  // issue prologue DMA early: halves H0,H1,H2 -> slots 0,1,2 (overlap gather)
  stageA<3>(wpack + 0,     ring[0], t);   // H0: L0 k0-2 (12KB)
  stageA<2>(wpack + 6144,  ring[1], t);   // H1: L0 k3-4 (8KB)
  stageA<4>(wpack + 10240, ring[2], t);   // H2: L1 k0-3 (16KB)
  // all 800 bias floats -> LDS (400 float2, strided over 256 threads)
  for (int i = t; i < 400; i += 256)
    ((float2*)blds)[i] = ((const float2*)bpack)[i];

  // ---- phase 1: gather + freq encode, directly into B-frag registers ----
  float cx = coords[pg * 3 + 0], cy = coords[pg * 3 + 1], cz = coords[pg * 3 + 2];
  float f1x = cx + 1.0f, f1y = cy + 1.0f, f1z = cz + 1.0f;
  float nx = f1x * 0.5f, ny = f1y * 0.5f, nz = f1z * 0.5f;
  float sx = f1x - 1.0f, sy = f1y - 1.0f, sz = f1z - 1.0f;
  bool sel = (nx > 0.f) & (nx < 1.f) & (ny > 0.f) & (ny < 1.f) & (nz > 0.f) & (nz < 1.f);
  const int b = pg >> 16;
  float acc[16];
#pragma unroll
  for (int j = 0; j < 16; ++j) acc[j] = 0.f;
#pragma unroll
  for (int pl = 0; pl < 3; ++pl) {
    float gx = (pl == 2) ? sy : sx;
    float gy = (pl == 0) ? sy : sz;
    float ix = ((gx + 1.0f) * 0.5f) * 255.0f;
    float iy = ((gy + 1.0f) * 0.5f) * 255.0f;
    float x0f = floorf(ix), y0f = floorf(iy);
    float wx = ix - x0f, wy = iy - y0f;
    float vx0 = (x0f >= 0.0f && x0f < 256.0f) ? 1.f : 0.f;
    float vx1 = (x0f >= -1.0f && x0f < 255.0f) ? 1.f : 0.f;
    float vy0 = (y0f >= 0.0f && y0f < 256.0f) ? 1.f : 0.f;
    float vy1 = (y0f >= -1.0f && y0f < 255.0f) ? 1.f : 0.f;
    int x0 = min(max((int)x0f, 0), 255), x1 = min(max((int)x0f + 1, 0), 255);
    int y0 = min(max((int)y0f, 0), 255), y1 = min(max((int)y0f + 1, 0), 255);
    float w00 = (1.f - wx) * (1.f - wy) * vx0 * vy0;
    float w10 = wx * (1.f - wy) * vx1 * vy0;
    float w01 = (1.f - wx) * wy * vx0 * vy1;
    float w11 = wx * wy * vx1 * vy1;
    const int n = 3 * b + pl;
    if (fast) {
      // lane's channel chunks: [kh*8, kh*8+8) and [16+kh*8, ...)
      const uint16_t* cb = trit + ((size_t)n << 21) + kh * 8;
      size_t o00 = (size_t)(y0 * 256 + x0) << 5, o10 = (size_t)(y0 * 256 + x1) << 5;
      size_t o01 = (size_t)(y1 * 256 + x0) << 5, o11 = (size_t)(y1 * 256 + x1) << 5;
      gacc(cb + o00, w00, acc); gacc(cb + 16 + o00, w00, acc + 8);
      gacc(cb + o10, w10, acc); gacc(cb + 16 + o10, w10, acc + 8);
      gacc(cb + o01, w01, acc); gacc(cb + 16 + o01, w01, acc + 8);
      gacc(cb + o11, w11, acc); gacc(cb + 16 + o11, w11, acc + 8);
    } else {
      const float* basef = trif + (((size_t)n * 32) << 16);
#pragma unroll
      for (int j = 0; j < 8; ++j) {
        const float* c0p = basef + (((size_t)(kh * 8 + j)) << 16);
        const float* c1p = basef + (((size_t)(16 + kh * 8 + j)) << 16);
        acc[j] += w00 * c0p[y0 * 256 + x0] + w10 * c0p[y0 * 256 + x1] +
                  w01 * c0p[y1 * 256 + x0] + w11 * c0p[y1 * 256 + x1];
        acc[8 + j] += w00 * c1p[y0 * 256 + x0] + w10 * c1p[y0 * 256 + x1] +
                      w01 * c1p[y1 * 256 + x0] + w11 * c1p[y1 * 256 + x1];
      }
    }
  }
  short8 hf[5];
  hf[0] = __builtin_bit_cast(
      short8, make_uint4(pack2(acc[0], acc[1]), pack2(acc[2], acc[3]),
                         pack2(acc[4], acc[5]), pack2(acc[6], acc[7])));
  hf[1] = __builtin_bit_cast(
      short8, make_uint4(pack2(acc[8], acc[9]), pack2(acc[10], acc[11]),
                         pack2(acc[12], acc[13]), pack2(acc[14], acc[15])));
  {
    // freq cols 32+e, e = d*12 + (sin: k | cos: 6+k)
    float sv[3][6], cv[3][6];
#pragma unroll
    for (int d = 0; d < 3; ++d) {
      float nd = (d == 0) ? nx : (d == 1) ? ny : nz;
#pragma unroll
      for (int k = 0; k < 6; ++k) {
        float rev = nd * (0.5f * (float)(1 << k));
        float r = rev - rintf(rev);
        sv[d][k] = __builtin_amdgcn_sinf(r);
        cv[d][k] = __builtin_amdgcn_cosf(r);
      }
    }
    if (kh == 0) {
      hf[2] = __builtin_bit_cast(  // e 0..7: d0 s0-5, d0 c0-1
          short8, make_uint4(pack2(sv[0][0], sv[0][1]), pack2(sv[0][2], sv[0][3]),
                             pack2(sv[0][4], sv[0][5]), pack2(cv[0][0], cv[0][1])));
      hf[3] = __builtin_bit_cast(  // e 16..23: d1 s4-5, d1 c0-5
          short8, make_uint4(pack2(sv[1][4], sv[1][5]), pack2(cv[1][0], cv[1][1]),
                             pack2(cv[1][2], cv[1][3]), pack2(cv[1][4], cv[1][5])));
      hf[4] = __builtin_bit_cast(  // e 32..35: d2 c2-5, then pad
          short8, make_uint4(pack2(cv[2][2], cv[2][3]), pack2(cv[2][4], cv[2][5]), 0u, 0u));
    } else {
      hf[2] = __builtin_bit_cast(  // e 8..15: d0 c2-5, d1 s0-3
          short8, make_uint4(pack2(cv[0][2], cv[0][3]), pack2(cv[0][4], cv[0][5]),
                             pack2(sv[1][0], sv[1][1]), pack2(sv[1][2], sv[1][3])));
      hf[3] = __builtin_bit_cast(  // e 24..31: d2 s0-5, d2 c0-1
          short8, make_uint4(pack2(sv[2][0], sv[2][1]), pack2(sv[2][2], sv[2][3]),
                             pack2(sv[2][4], sv[2][5]), pack2(cv[2][0], cv[2][1])));
      hf[4] = __builtin_bit_cast(short8, make_uint4(0u, 0u, 0u, 0u));
    }
  }

  // ---- phase 2: MLP; half-layer ring pipeline, stages issued 3 halves ahead ----
  __syncthreads();  // drains prologue DMA (H0-H2), bias copy, gather loads
  floatx16 a[4];
  short8 bf[8];

  // L0 (Ks 3+2)
  acc_init4(a, blds, 0, kh);
  chunk4<3>(a, hf, ring[0], L);                       // H0
  bar_keep<0>(); stageA<4>(wpack + 18432, ring[0], t);  // H3
  chunk4<2>(a, hf + 3, ring[1], L);                   // H1
  bar_keep<4>(); stageA<4>(wpack + 26624, ring[1], t);  // H4
  epi_dense(a, bf);

  // L1 (4+4)
  acc_init4(a, blds, 1, kh);
  chunk4<4>(a, bf, ring[2], L);                       // H2
  bar_keep<4>(); stageA<4>(wpack + 34816, ring[2], t);  // H5
  chunk4<4>(a, bf + 4, ring[0], L);                   // H3
  bar_keep<4>(); stageA<3>(wpack + 43008, ring[0], t);  // H6
  epi_dense(a, bf);

  // L2 (4+4)
  acc_init4(a, blds, 2, kh);
  chunk4<4>(a, bf, ring[1], L);                       // H4
  bar_keep<3>(); stageA<2>(wpack + 49152, ring[1], t);  // H7
  chunk4<4>(a, bf + 4, ring[2], L);                   // H5
  bar_keep<2>(); stageA<4>(wpack + 53248, ring[2], t);  // H8
  epi_dense(a, bf);

  // L3 skip (3+2)
  acc_init4(a, blds, 3, kh);
  chunk4<3>(a, hf, ring[0], L);                       // H6
  bar_keep<4>(); stageA<4>(wpack + 61440, ring[0], t);  // H9
  chunk4<2>(a, hf + 3, ring[1], L);                   // H7
  bar_keep<4>(); stageA<4>(wpack + 69632, ring[1], t);  // H10
  epi_skip(a, bf);

  // L4 (4+4)
  acc_init4(a, blds, 4, kh);
  chunk4<4>(a, bf, ring[2], L);                       // H8
  bar_keep<4>(); stageA<4>(wpack + 77824, ring[2], t);  // H11
  chunk4<4>(a, bf + 4, ring[0], L);                   // H9
  bar_keep<4>(); stageA<1>(wpack + 86016, ring[0], t);  // H12
  epi_dense(a, bf);

  // L5 (4+4)
  acc_init4(a, blds, 5, kh);
  chunk4<4>(a, bf, ring[1], L);                       // H10
  bar_keep<1>(); stageA<1>(wpack + 88064, ring[1], t);  // H13
  chunk4<4>(a, bf + 4, ring[2], L);                   // H11
  bar_keep<1>();
  epi_dense(a, bf);

  // ---- output layer: w_out padded to 32x128, only rows 0..3 real ----
  {
    floatx16 ao;
    const float4* bp = (const float4*)(blds + 768 + kh * 16);
#pragma unroll
    for (int g = 0; g < 4; ++g) {
      float4 v = bp[g];
      ao[4 * g + 0] = v.x; ao[4 * g + 1] = v.y; ao[4 * g + 2] = v.z; ao[4 * g + 3] = v.w;
    }
    {
      const uint16_t* wp = ring[0] + L * 8;                // H12: k0-3
#pragma unroll
      for (int k = 0; k < 4; ++k) {
        short8 af = *(const short8*)(wp + (size_t)k * 512);
        ao = __builtin_amdgcn_mfma_f32_32x32x16_bf16(af, bf[k], ao, 0, 0, 0);
      }
    }
    bar_keep<0>();  // H13 staged by all waves, drained
    {
      const uint16_t* wp = ring[1] + L * 8;                // H13: k4-7
#pragma unroll
      for (int k = 0; k < 4; ++k) {
        short8 af = *(const short8*)(wp + (size_t)k * 512);
        ao = __builtin_amdgcn_mfma_f32_32x32x16_bf16(af, bf[4 + k], ao, 0, 0, 0);
      }
    }
    if (kh == 0) {  // regs 0..3 = out features 0..3 for point pg
      const float l2e = 1.44269504f;
      float r0 = 1.0f / (1.0f + exp2f(-l2e * ao[0]));
      float r1 = 1.0f / (1.0f + exp2f(-l2e * ao[1]));
      float r2 = 1.0f / (1.0f + exp2f(-l2e * ao[2]));
      float dens = exp2f((ao[3] - 1.0f) * l2e) * (sel ? 1.0f : 0.0f);
      dout[pg * 3 + 0] = r0;
      dout[pg * 3 + 1] = r1;
      dout[pg * 3 + 2] = r2;
      dout[RGB_OFF + pg] = dens;
    }
  }
}

extern "C" void kernel_launch(void* const* d_in, const int* in_sizes, int n_in,
                              void* d_out, int out_size, void* d_ws, size_t ws_size,
                              hipStream_t stream) {
  const float* tri = (const float*)d_in[0];
  const float* coords = (const float*)d_in[1];
  const float* w_in = (const float*)d_in[2];
  const float* b_in = (const float*)d_in[3];
  const float* w_skip = (const float*)d_in[4];
  const float* b_skip = (const float*)d_in[5];
  const float* w_bef = (const float*)d_in[6];
  const float* b_bef = (const float*)d_in[7];
  const float* w_aft = (const float*)d_in[8];
  const float* b_aft = (const float*)d_in[9];
  const float* w_out = (const float*)d_in[10];
  const float* b_out = (const float*)d_in[11];
  const size_t TRI_B = (size_t)12 * 256 * 256 * 32 * 2;  // 50,331,648
  const size_t WP_B = (size_t)176 * 1024;                // 180,224
  const size_t BP_B = 3200;
  char* ws = (char*)d_ws;
  const int fast = (ws_size >= TRI_B + WP_B + BP_B) ? 1 : 0;
  uint16_t* trit;
  uint16_t* wpk;
  float* bpk;
  if (fast) {
    trit = (uint16_t*)ws;
    wpk = (uint16_t*)(ws + TRI_B);
    bpk = (float*)(ws + TRI_B + WP_B);
  } else {
    trit = (uint16_t*)ws;  // unused
    wpk = (uint16_t*)ws;
    bpk = (float*)(ws + WP_B);
  }
  if (fast) k_tr<<<dim3(3072), dim3(256), 0, stream>>>(tri, trit);
  k_pack<<<dim3(45), dim3(256), 0, stream>>>(w_in, w_skip, w_bef, w_aft, w_out,
                                             b_in, b_skip, b_bef, b_aft, b_out,
                                             wpk, bpk);
  k_main<<<dim3(2048), dim3(256), 0, stream>>>(trit, tri, coords, wpk, bpk,
                                               (float*)d_out, fast);
}